// Round 4
// baseline (108.522 us; speedup 1.0000x reference)
//
#include <hip/hip_runtime.h>
#include <hip/hip_bf16.h>
#include <math.h>

typedef __attribute__((ext_vector_type(8))) short short8;
typedef __attribute__((ext_vector_type(4))) short short4v;
typedef __attribute__((ext_vector_type(4))) float f32x4;
typedef __attribute__((ext_vector_type(4))) int int4v;

#define XP 1032

__device__ __forceinline__ short f2b(float v) {
  unsigned int u = __builtin_bit_cast(unsigned int, v);
  unsigned int r = (u + 0x7fffu + ((u >> 16) & 1u)) >> 16;
  return (short)(unsigned short)r;
}
__device__ __forceinline__ int rol10(int x, int k) {
  return ((x << k) | (x >> (10 - k))) & 1023;
}
__device__ __forceinline__ int ror10(int x, int k) {
  return ((x >> k) | (x << (10 - k))) & 1023;
}
__device__ __forceinline__ int swzj(int j) {
  return j ^ (((j >> 6) & 7) << 3);
}

// ------------------------------------------------------------------
// Kernel 0: convert the four monarch weight tensors fp32 -> bf16.
// Lbf layout: [slot][131072], slot = {M1L, M1R, M2L, M2R}.
// ------------------------------------------------------------------
__global__ __launch_bounds__(256) void conv_lr(
    const float* __restrict__ M1L, const float* __restrict__ M1R,
    const float* __restrict__ M2L, const float* __restrict__ M2R,
    short* __restrict__ Lbf)
{
  int g = blockIdx.x * 256 + threadIdx.x;   // 0..32767, 4 floats each
  const float* srcs[4] = {M1L, M1R, M2L, M2R};
  #pragma unroll
  for (int t = 0; t < 4; ++t) {
    float4 v = *(const float4*)(srcs[t] + (size_t)g * 4);
    short4v o = { f2b(v.x), f2b(v.y), f2b(v.z), f2b(v.w) };
    *(short4v*)(Lbf + (size_t)t * 131072 + (size_t)g * 4) = o;
  }
}

// ------------------------------------------------------------------
// Kernel 1: monarch transform, one block per (bh, src, dc, i).
// XCD-affine decode: xcd = blk&7 owns bh group xcd*4..xcd*4+3 (same
// grouping as score_gemm, so Qhat/Khat panels stay in that XCD's L2).
// Writes Qhat/Khat bf16 [bh][s=1024][kd=256], kd = i*64 + dc*16 + d.
// softmax(weights) folded into Qhat.
// ------------------------------------------------------------------
template<bool USEBF>
__global__ __launch_bounds__(256) void monarch_transform2(
    const float* __restrict__ Q, const float* __restrict__ Kv,
    const float* __restrict__ M1L, const float* __restrict__ M1R,
    const float* __restrict__ M2L, const float* __restrict__ M2R,
    const short* __restrict__ Lbf,
    const float* __restrict__ W, const int* __restrict__ periods,
    short* __restrict__ Qh, short* __restrict__ Kh)
{
  const int blk  = blockIdx.x;
  const int xcd  = blk & 7;
  const int seq  = blk >> 3;
  const int bh   = (xcd << 2) | (seq & 3);
  const int i    = (seq >> 2) & 3;
  const int src  = (seq >> 4) & 1;
  const int dc   = (seq >> 5) & 3;
  const int b    = bh >> 3;
  const int h    = bh & 7;

  __shared__ short xb[16 * XP];    // 33 KB; reused as xb2[1024][16] at the end

  const int tid  = threadIdx.x;
  const int lane = tid & 63;
  const int w    = tid >> 6;
  const int l15  = lane & 15;
  const int l4   = lane >> 4;

  const int p   = periods[i];           // {1,2,4,8}
  const int lp  = 31 - __clz(p);
  const int kin = 5 + lp;               // input rotation
  const int kf  = 5 - lp;               // output rotation

  float scale = 1.0f;
  if (src == 0) {
    float w0 = W[b*4+0], w1 = W[b*4+1], w2 = W[b*4+2], w3 = W[b*4+3];
    float mx = fmaxf(fmaxf(w0, w1), fmaxf(w2, w3));
    float e0 = expf(w0-mx), e1 = expf(w1-mx), e2 = expf(w2-mx), e3 = expf(w3-mx);
    float inv = 1.0f / (e0+e1+e2+e3);
    float e[4] = {e0, e1, e2, e3};
    scale = e[i] * inv;
  }

  // ---- Phase 1: coalesced load of X, stage into LDS in t2 order ----
  // t2[d][j] = x[d][ror10(j, kin)]  =>  write x[d][s] at j = rol10(s, kin)
  {
    const int dgrp = tid & 3;           // which float4 of the 16-d chunk
    const int srow = tid >> 2;          // 0..63
    const float* xbase = (src ? Kv : Q)
        + (size_t)b*524288 + h*64 + dc*16 + dgrp*4;
    const int jlo = rol10(srow, kin);   // srow bits (0..5) rotated
    #pragma unroll
    for (int it = 0; it < 16; ++it) {
      int s = it*64 + srow;
      float4 v = *(const float4*)(xbase + (size_t)s * 512);
      int j  = rol10(it << 6, kin) | jlo;   // disjoint bit fields
      int ja = swzj(j);
      xb[(dgrp*4+0)*XP + ja] = f2b(v.x);
      xb[(dgrp*4+1)*XP + ja] = f2b(v.y);
      xb[(dgrp*4+2)*XP + ja] = f2b(v.z);
      xb[(dgrp*4+3)*XP + ja] = f2b(v.w);
    }
  }
  __syncthreads();

  const short* LBs = Lbf + (size_t)(src ? 2 : 0) * 131072;  // L slot
  const short* RBs = Lbf + (size_t)(src ? 3 : 1) * 131072;  // R slot
  const float* LF  = src ? M2L : M1L;
  const float* RF  = src ? M2R : M1R;

  f32x4 acc[8][2];

  // ---- Stage 1: t3 = blockdiag(L) * t2 ----
  #pragma unroll
  for (int bi = 0; bi < 8; ++bi)
    #pragma unroll
    for (int rt = 0; rt < 2; ++rt) acc[bi][rt] = (f32x4){0.f,0.f,0.f,0.f};

  #pragma unroll
  for (int bi = 0; bi < 8; ++bi) {
    int bb = w*8 + bi;
    int j0 = bb*32 + l4*8;
    short8 a = *(const short8*)&xb[l15*XP + swzj(j0)];
    #pragma unroll
    for (int rt = 0; rt < 2; ++rt) {
      int roff = ((i*32 + bb)*32 + rt*16 + l15)*32 + l4*8;
      short8 bf;
      if (USEBF) {
        bf = *(const short8*)(LBs + roff);
      } else {
        float4 u0 = *(const float4*)(LF + roff);
        float4 u1 = *(const float4*)(LF + roff + 4);
        bf[0]=f2b(u0.x); bf[1]=f2b(u0.y); bf[2]=f2b(u0.z); bf[3]=f2b(u0.w);
        bf[4]=f2b(u1.x); bf[5]=f2b(u1.y); bf[6]=f2b(u1.z); bf[7]=f2b(u1.w);
      }
      acc[bi][rt] = __builtin_amdgcn_mfma_f32_16x16x32_bf16(a, bf, acc[bi][rt], 0, 0, 0);
    }
  }
  __syncthreads();

  // ---- t4 pack-write: t4[d][r*32+bb] = t3[bb*32+r]; 8 consecutive j per lane ----
  #pragma unroll
  for (int rt = 0; rt < 2; ++rt)
    #pragma unroll
    for (int rr = 0; rr < 4; ++rr) {
      short8 v;
      #pragma unroll
      for (int bi = 0; bi < 8; ++bi) v[bi] = f2b(acc[bi][rt][rr]);
      int r  = rt*16 + l15;
      int d  = l4*4 + rr;
      int j2 = r*32 + w*8;
      *(short8*)&xb[d*XP + swzj(j2)] = v;
    }
  __syncthreads();

  // ---- Stage 2: t5 = blockdiag(R) * t4 ----
  #pragma unroll
  for (int bi = 0; bi < 8; ++bi)
    #pragma unroll
    for (int rt = 0; rt < 2; ++rt) acc[bi][rt] = (f32x4){0.f,0.f,0.f,0.f};

  #pragma unroll
  for (int bi = 0; bi < 8; ++bi) {
    int bb = w*8 + bi;
    int j0 = bb*32 + l4*8;
    short8 a = *(const short8*)&xb[l15*XP + swzj(j0)];
    #pragma unroll
    for (int rt = 0; rt < 2; ++rt) {
      int roff = ((i*32 + bb)*32 + rt*16 + l15)*32 + l4*8;
      short8 bf;
      if (USEBF) {
        bf = *(const short8*)(RBs + roff);
      } else {
        float4 u0 = *(const float4*)(RF + roff);
        float4 u1 = *(const float4*)(RF + roff + 4);
        bf[0]=f2b(u0.x); bf[1]=f2b(u0.y); bf[2]=f2b(u0.z); bf[3]=f2b(u0.w);
        bf[4]=f2b(u1.x); bf[5]=f2b(u1.y); bf[6]=f2b(u1.z); bf[7]=f2b(u1.w);
      }
      acc[bi][rt] = __builtin_amdgcn_mfma_f32_16x16x32_bf16(a, bf, acc[bi][rt], 0, 0, 0);
    }
  }
  __syncthreads();

  // ---- Phase 5: scatter t5 -> xb2[jo][16 d] (b64, swizzled), scaled ----
  // t5 index m = bb2*32 + r2 lands at jo = ror10(m, kf)
  #pragma unroll
  for (int bi = 0; bi < 8; ++bi)
    #pragma unroll
    for (int rt = 0; rt < 2; ++rt) {
      int m  = (w*8 + bi)*32 + rt*16 + l15;
      int jo = ror10(m, kf);
      int sw = (jo >> 5) & 3;
      unsigned int lo = (unsigned short)f2b(acc[bi][rt][0] * scale)
                      | ((unsigned int)(unsigned short)f2b(acc[bi][rt][1] * scale) << 16);
      unsigned int hi = (unsigned short)f2b(acc[bi][rt][2] * scale)
                      | ((unsigned int)(unsigned short)f2b(acc[bi][rt][3] * scale) << 16);
      uint2 pv; pv.x = lo; pv.y = hi;
      *(uint2*)&xb[jo*16 + ((l4 ^ sw) << 2)] = pv;   // d-group l4 stored at (l4^sw)
    }
  __syncthreads();

  // ---- Phase 6: coalesced global write [s][kd] ----
  {
    short* Out = src ? Kh : Qh;
    size_t obase = ((size_t)bh * 1024) * 256 + i*64 + dc*16;
    #pragma unroll
    for (int it2 = 0; it2 < 4; ++it2) {
      int jo = it2*256 + tid;
      int sw = (jo >> 5) & 3;
      uint2 g[4];
      #pragma unroll
      for (int gg = 0; gg < 4; ++gg)
        g[gg] = *(const uint2*)&xb[jo*16 + (((gg ^ sw)) << 2)];
      int4v lo = {(int)g[0].x, (int)g[0].y, (int)g[1].x, (int)g[1].y};
      int4v hi = {(int)g[2].x, (int)g[2].y, (int)g[3].x, (int)g[3].y};
      short* op = Out + obase + (size_t)jo * 256;
      *(int4v*)(op)     = lo;
      *(int4v*)(op + 8) = hi;
    }
  }
}

// ------------------------------------------------------------------
// Kernel 2: batched GEMM  out[s,l] = sum_k Qhat[s,k]*Khat[l,k], K=256,
// 128x128 tiles, NO LDS: fragments load directly global->VGPR (panels
// are XCD-L2-resident: xcd = bid&7 owns bh group xcd*4..+3 = 4MB).
// Zero barriers, zero waitcnt-drains; 8 independent k-chunks give the
// scheduler pure dataflow. Swapped-operand MFMA -> float4 nt stores.
// ------------------------------------------------------------------
__global__ __launch_bounds__(256) void score_gemm(
    const short* __restrict__ Qh, const short* __restrict__ Kh,
    float* __restrict__ Out)
{
  const int bid  = blockIdx.x;
  const int xcd  = bid & 7;
  const int seq  = bid >> 3;
  const int bh   = (xcd << 2) | (seq & 3);
  const int tile = seq >> 2;               // 0..63
  const int tm   = (tile >> 3) << 7;
  const int tn   = (tile & 7) << 7;

  const int tid  = threadIdx.x;
  const int lane = tid & 63;
  const int w    = tid >> 6;
  const int wm   = (w >> 1) << 6;
  const int wn   = (w & 1) << 6;
  const int l15  = lane & 15;
  const int l4   = lane >> 4;

  const short* Qb = Qh + (size_t)bh * (1024*256);
  const short* Kb = Kh + (size_t)bh * (1024*256);

  const short* qa[4];
  const short* kb[4];
  #pragma unroll
  for (int fm = 0; fm < 4; ++fm)
    qa[fm] = Qb + (size_t)(tm + wm + fm*16 + l15) * 256 + l4*8;
  #pragma unroll
  for (int fn = 0; fn < 4; ++fn)
    kb[fn] = Kb + (size_t)(tn + wn + fn*16 + l15) * 256 + l4*8;

  f32x4 acc[4][4];
  #pragma unroll
  for (int fm = 0; fm < 4; ++fm)
    #pragma unroll
    for (int fn = 0; fn < 4; ++fn) acc[fm][fn] = (f32x4){0.f,0.f,0.f,0.f};

  #pragma unroll 2
  for (int kt = 0; kt < 8; ++kt) {         // 8 chunks of K=32
    short8 af[4], bf[4];
    #pragma unroll
    for (int fm = 0; fm < 4; ++fm)
      af[fm] = *(const short8*)(qa[fm] + kt*32);
    #pragma unroll
    for (int fn = 0; fn < 4; ++fn)
      bf[fn] = *(const short8*)(kb[fn] + kt*32);
    // swapped operands: D rows = K-side (l), D cols = Q-side (s)
    #pragma unroll
    for (int fm = 0; fm < 4; ++fm)
      #pragma unroll
      for (int fn = 0; fn < 4; ++fn)
        acc[fm][fn] = __builtin_amdgcn_mfma_f32_16x16x32_bf16(bf[fn], af[fm], acc[fm][fn], 0, 0, 0);
  }

  // Epilogue: lane holds 4 consecutive l at fixed s -> float4 nt stores.
  float* Ob = Out + ((size_t)bh << 20);
  #pragma unroll
  for (int fm = 0; fm < 4; ++fm) {
    int srow = tm + wm + fm*16 + l15;
    #pragma unroll
    for (int fn = 0; fn < 4; ++fn) {
      int lcol = tn + wn + fn*16 + l4*4;
      __builtin_nontemporal_store(acc[fm][fn],
          (f32x4*)(Ob + ((size_t)srow << 10) + lcol));
    }
  }
}

extern "C" void kernel_launch(void* const* d_in, const int* in_sizes, int n_in,
                              void* d_out, int out_size, void* d_ws, size_t ws_size,
                              hipStream_t stream) {
  const float* Q   = (const float*)d_in[0];
  const float* Kv  = (const float*)d_in[1];
  const float* M1L = (const float*)d_in[2];
  const float* M1R = (const float*)d_in[3];
  const float* M2L = (const float*)d_in[4];
  const float* M2R = (const float*)d_in[5];
  const float* W   = (const float*)d_in[6];
  const int* per   = (const int*)d_in[7];
  float* Out       = (float*)d_out;

  const size_t qsz = (size_t)32 * 1024 * 256;     // 8388608 shorts each
  short* Qhat = (short*)d_ws;
  short* Khat = Qhat + qsz;
  short* Lbf  = Khat + qsz;
  const size_t need = (qsz * 2 + (size_t)4 * 131072) * sizeof(short);
  const bool usebf = (ws_size >= need);

  if (usebf) {
    conv_lr<<<dim3(128), dim3(256), 0, stream>>>(M1L, M1R, M2L, M2R, Lbf);
    monarch_transform2<true><<<dim3(1024), dim3(256), 0, stream>>>(
        Q, Kv, M1L, M1R, M2L, M2R, Lbf, W, per, Qhat, Khat);
  } else {
    monarch_transform2<false><<<dim3(1024), dim3(256), 0, stream>>>(
        Q, Kv, M1L, M1R, M2L, M2R, Lbf, W, per, Qhat, Khat);
  }

  score_gemm<<<dim3(2048), dim3(256), 0, stream>>>(Qhat, Khat, Out);
}

// Round 5
// 78.850 us; speedup vs baseline: 1.3763x; 1.3763x over previous
//
#include <hip/hip_runtime.h>
#include <hip/hip_bf16.h>
#include <math.h>

typedef __attribute__((ext_vector_type(8))) short short8;
typedef __attribute__((ext_vector_type(4))) short short4v;
typedef __attribute__((ext_vector_type(4))) float f32x4;
typedef __attribute__((ext_vector_type(4))) int int4v;

#define XP 1032

__device__ __forceinline__ short f2b(float v) {
  unsigned int u = __builtin_bit_cast(unsigned int, v);
  unsigned int r = (u + 0x7fffu + ((u >> 16) & 1u)) >> 16;
  return (short)(unsigned short)r;
}
__device__ __forceinline__ int ror10(int x, int k) {
  return ((x >> k) | (x << (10 - k))) & 1023;
}
__device__ __forceinline__ int swzj(int j) {
  return j ^ (((j >> 6) & 7) << 3);
}

// ------------------------------------------------------------------
// Kernel 0: convert the four monarch weight tensors fp32 -> bf16.
// Lbf layout: [slot][131072], slot = {M1L, M1R, M2L, M2R}.
// ------------------------------------------------------------------
__global__ __launch_bounds__(256) void conv_lr(
    const float* __restrict__ M1L, const float* __restrict__ M1R,
    const float* __restrict__ M2L, const float* __restrict__ M2R,
    short* __restrict__ Lbf)
{
  int g = blockIdx.x * 256 + threadIdx.x;   // 0..32767, 4 floats each
  const float* srcs[4] = {M1L, M1R, M2L, M2R};
  #pragma unroll
  for (int t = 0; t < 4; ++t) {
    float4 v = *(const float4*)(srcs[t] + (size_t)g * 4);
    short4v o = { f2b(v.x), f2b(v.y), f2b(v.z), f2b(v.w) };
    *(short4v*)(Lbf + (size_t)t * 131072 + (size_t)g * 4) = o;
  }
}

// ------------------------------------------------------------------
// Kernel 1: monarch transform v3. One block per (bh, src, dc);
// 512 threads (8 waves), ALL 4 components computed from ONE raw
// bf16 LDS image of the X slice (single HBM read per slice).
// Stage-1 A-fragments gather directly from raw via the rotation
// s = ror10(j,kin); consecutive e -> s0 + e*(1<<(10-kin)).
// XCD affinity: bid&7 == bh>>2 (matches score_gemm ownership).
// Writes Qhat/Khat bf16 [bh][s=1024][kd=256], kd = i*64 + dc*16 + d.
// ------------------------------------------------------------------
template<bool USEBF>
__global__ __launch_bounds__(512) void monarch_transform3(
    const float* __restrict__ Q, const float* __restrict__ Kv,
    const float* __restrict__ M1L, const float* __restrict__ M1R,
    const float* __restrict__ M2L, const float* __restrict__ M2R,
    const short* __restrict__ Lbf,
    const float* __restrict__ W, const int* __restrict__ periods,
    short* __restrict__ Qh, short* __restrict__ Kh)
{
  const int bid = blockIdx.x;
  const int xcd = bid & 7;
  const int seq = bid >> 3;          // 0..31
  const int bh  = (xcd << 2) | (seq & 3);
  const int src = (seq >> 2) & 1;
  const int dc  = (seq >> 3) & 3;
  const int b   = bh >> 3;
  const int h   = bh & 7;

  __shared__ short raw[16 * XP];     // 33 KB: raw bf16 [16 d][1024 s]
  __shared__ short scr[16 * XP];     // 33 KB: t4 scratch / output transpose

  const int tid  = threadIdx.x;
  const int lane = tid & 63;
  const int w    = tid >> 6;         // 0..7
  const int l15  = lane & 15;
  const int l4   = lane >> 4;

  // softmax weights (folded into Q side)
  float ws[4];
  {
    float w0 = W[b*4+0], w1 = W[b*4+1], w2 = W[b*4+2], w3 = W[b*4+3];
    float mx = fmaxf(fmaxf(w0, w1), fmaxf(w2, w3));
    float e0 = expf(w0-mx), e1 = expf(w1-mx), e2 = expf(w2-mx), e3 = expf(w3-mx);
    float inv = 1.0f / (e0+e1+e2+e3);
    ws[0]=e0*inv; ws[1]=e1*inv; ws[2]=e2*inv; ws[3]=e3*inv;
  }

  // ---- Staging: coalesced float4 load of X slice -> raw[d][s] bf16 ----
  {
    const int dgrp = tid & 3;          // which float4 of the 16-d chunk
    const int srow = tid >> 2;         // 0..127
    const float* xbase = (src ? Kv : Q)
        + (size_t)b*524288 + h*64 + dc*16 + dgrp*4;
    #pragma unroll
    for (int it = 0; it < 8; ++it) {
      int s = it*128 + srow;
      float4 v = *(const float4*)(xbase + (size_t)s * 512);
      raw[(dgrp*4+0)*XP + s] = f2b(v.x);
      raw[(dgrp*4+1)*XP + s] = f2b(v.y);
      raw[(dgrp*4+2)*XP + s] = f2b(v.z);
      raw[(dgrp*4+3)*XP + s] = f2b(v.w);
    }
  }
  __syncthreads();

  const short* LBs = Lbf + (size_t)(src ? 2 : 0) * 131072;
  const short* RBs = Lbf + (size_t)(src ? 3 : 1) * 131072;
  const float* LF  = src ? M2L : M1L;
  const float* RF  = src ? M2R : M1R;
  short* Out       = src ? Kh : Qh;

  for (int i = 0; i < 4; ++i) {
    const int p    = periods[i];          // {1,2,4,8}
    const int lp   = 31 - __clz(p);
    const int kin  = 5 + lp;
    const int kf   = 5 - lp;
    const int str  = 1 << (10 - kin);
    const int mask = (1 << kin) - 1;
    const float scale = (src == 0) ? ws[i] : 1.0f;

    // ---- Stage 1: t3 = blockdiag(L) * t2, A gathered from raw ----
    f32x4 acc[4][2];
    #pragma unroll
    for (int bi = 0; bi < 4; ++bi)
      #pragma unroll
      for (int rt = 0; rt < 2; ++rt) acc[bi][rt] = (f32x4){0.f,0.f,0.f,0.f};

    #pragma unroll
    for (int bi = 0; bi < 4; ++bi) {
      int bb = w*4 + bi;
      int j0 = bb*32 + l4*8;
      int s0 = (j0 >> kin) | ((j0 & mask) << (10 - kin));
      short8 a;
      #pragma unroll
      for (int e = 0; e < 8; ++e) a[e] = raw[l15*XP + s0 + e*str];
      #pragma unroll
      for (int rt = 0; rt < 2; ++rt) {
        int roff = ((i*32 + bb)*32 + rt*16 + l15)*32 + l4*8;
        short8 bf;
        if (USEBF) {
          bf = *(const short8*)(LBs + roff);
        } else {
          float4 u0 = *(const float4*)(LF + roff);
          float4 u1 = *(const float4*)(LF + roff + 4);
          bf[0]=f2b(u0.x); bf[1]=f2b(u0.y); bf[2]=f2b(u0.z); bf[3]=f2b(u0.w);
          bf[4]=f2b(u1.x); bf[5]=f2b(u1.y); bf[6]=f2b(u1.z); bf[7]=f2b(u1.w);
        }
        acc[bi][rt] = __builtin_amdgcn_mfma_f32_16x16x32_bf16(a, bf, acc[bi][rt], 0, 0, 0);
      }
    }

    // ---- t4 pack-write: t4[d][r*32+bb] = t3[bb*32+r] (b64, swizzled) ----
    #pragma unroll
    for (int rt = 0; rt < 2; ++rt)
      #pragma unroll
      for (int rr = 0; rr < 4; ++rr) {
        short4v v;
        #pragma unroll
        for (int bi = 0; bi < 4; ++bi) v[bi] = f2b(acc[bi][rt][rr]);
        int r  = rt*16 + l15;
        int d  = l4*4 + rr;
        int j2 = r*32 + w*4;
        *(short4v*)&scr[d*XP + swzj(j2)] = v;
      }
    __syncthreads();

    // ---- Stage 2: t5 = blockdiag(R) * t4 ----
    f32x4 ac2[4][2];
    #pragma unroll
    for (int bi = 0; bi < 4; ++bi)
      #pragma unroll
      for (int rt = 0; rt < 2; ++rt) ac2[bi][rt] = (f32x4){0.f,0.f,0.f,0.f};

    #pragma unroll
    for (int bi = 0; bi < 4; ++bi) {
      int bb = w*4 + bi;
      int j0 = bb*32 + l4*8;
      short8 a = *(const short8*)&scr[l15*XP + swzj(j0)];
      #pragma unroll
      for (int rt = 0; rt < 2; ++rt) {
        int roff = ((i*32 + bb)*32 + rt*16 + l15)*32 + l4*8;
        short8 bf;
        if (USEBF) {
          bf = *(const short8*)(RBs + roff);
        } else {
          float4 u0 = *(const float4*)(RF + roff);
          float4 u1 = *(const float4*)(RF + roff + 4);
          bf[0]=f2b(u0.x); bf[1]=f2b(u0.y); bf[2]=f2b(u0.z); bf[3]=f2b(u0.w);
          bf[4]=f2b(u1.x); bf[5]=f2b(u1.y); bf[6]=f2b(u1.z); bf[7]=f2b(u1.w);
        }
        ac2[bi][rt] = __builtin_amdgcn_mfma_f32_16x16x32_bf16(a, bf, ac2[bi][rt], 0, 0, 0);
      }
    }
    __syncthreads();

    // ---- Phase 5: scatter t5 -> scr[jo][16 d] (b64, d-group swizzled) ----
    #pragma unroll
    for (int bi = 0; bi < 4; ++bi)
      #pragma unroll
      for (int rt = 0; rt < 2; ++rt) {
        int m  = (w*4 + bi)*32 + rt*16 + l15;
        int jo = ror10(m, kf);
        int sw = (jo >> 5) & 3;
        unsigned int lo = (unsigned short)f2b(ac2[bi][rt][0] * scale)
                        | ((unsigned int)(unsigned short)f2b(ac2[bi][rt][1] * scale) << 16);
        unsigned int hi = (unsigned short)f2b(ac2[bi][rt][2] * scale)
                        | ((unsigned int)(unsigned short)f2b(ac2[bi][rt][3] * scale) << 16);
        uint2 pv; pv.x = lo; pv.y = hi;
        *(uint2*)&scr[jo*16 + ((l4 ^ sw) << 2)] = pv;
      }
    __syncthreads();

    // ---- Phase 6: coalesced global write [s][kd] ----
    {
      size_t obase = ((size_t)bh * 1024) * 256 + i*64 + dc*16;
      #pragma unroll
      for (int it2 = 0; it2 < 2; ++it2) {
        int jo = it2*512 + tid;
        int sw = (jo >> 5) & 3;
        uint2 g[4];
        #pragma unroll
        for (int gg = 0; gg < 4; ++gg)
          g[gg] = *(const uint2*)&scr[jo*16 + ((gg ^ sw) << 2)];
        int4v lo = {(int)g[0].x, (int)g[0].y, (int)g[1].x, (int)g[1].y};
        int4v hi = {(int)g[2].x, (int)g[2].y, (int)g[3].x, (int)g[3].y};
        short* op = Out + obase + (size_t)jo * 256;
        *(int4v*)(op)     = lo;
        *(int4v*)(op + 8) = hi;
      }
    }
    __syncthreads();   // protect scr for next component's t4 write
  }
}

// ------------------------------------------------------------------
// Kernel 2 (round-3 form): batched GEMM out[s,l] = sum_k Q[s,k]K[l,k],
// K=256, 128x128 tiles, LDS staging via global_load_lds w/ XOR swizzle.
// XCD-affine: xcd = bid&7 owns bh group xcd*4..+3 (4MB = one XCD L2).
// Swapped-operand MFMA -> float4 nontemporal stores.
// ------------------------------------------------------------------
__global__ __launch_bounds__(256) void score_gemm(
    const short* __restrict__ Qh, const short* __restrict__ Kh,
    float* __restrict__ Out)
{
  const int bid  = blockIdx.x;
  const int xcd  = bid & 7;
  const int seq  = bid >> 3;
  const int bh   = (xcd << 2) | (seq & 3);
  const int tile = seq >> 2;               // 0..63
  const int tm   = (tile >> 3) << 7;
  const int tn   = (tile & 7) << 7;

  __shared__ short As[128*64];
  __shared__ short Bs[128*64];

  const int tid  = threadIdx.x;
  const int lane = tid & 63;
  const int w    = tid >> 6;
  const int wm   = (w >> 1) << 6;
  const int wn   = (w & 1) << 6;
  const int l15  = lane & 15;
  const int l4   = lane >> 4;

  const short* Qb = Qh + (size_t)bh * (1024*256);
  const short* Kb = Kh + (size_t)bh * (1024*256);

  const int lrow = lane >> 3;                    // row within 8-row segment
  const int kch  = (((lane & 7) ^ lrow) << 3);   // inverse-swizzled source k-offset

  f32x4 acc[4][4];
  #pragma unroll
  for (int fm = 0; fm < 4; ++fm)
    #pragma unroll
    for (int fn = 0; fn < 4; ++fn) acc[fm][fn] = (f32x4){0.f,0.f,0.f,0.f};

  for (int kt = 0; kt < 4; ++kt) {
    #pragma unroll
    for (int q0 = 0; q0 < 4; ++q0) {
      int seg = w*4 + q0;
      int row = seg*8 + lrow;
      const short* srcA = Qb + (size_t)(tm + row)*256 + kt*64 + kch;
      const short* srcB = Kb + (size_t)(tn + row)*256 + kt*64 + kch;
      __builtin_amdgcn_global_load_lds(
          (const __attribute__((address_space(1))) unsigned int*)srcA,
          (__attribute__((address_space(3))) unsigned int*)&As[seg*512], 16, 0, 0);
      __builtin_amdgcn_global_load_lds(
          (const __attribute__((address_space(1))) unsigned int*)srcB,
          (__attribute__((address_space(3))) unsigned int*)&Bs[seg*512], 16, 0, 0);
    }
    __syncthreads();

    #pragma unroll
    for (int kk = 0; kk < 2; ++kk) {
      short8 af[4], bf[4];
      #pragma unroll
      for (int fm = 0; fm < 4; ++fm) {
        int row = wm + fm*16 + l15;
        int kl  = kk*32 + l4*8;
        af[fm] = *(const short8*)&As[row*64 + (kl ^ ((row & 7) << 3))];
      }
      #pragma unroll
      for (int fn = 0; fn < 4; ++fn) {
        int row = wn + fn*16 + l15;
        int kl  = kk*32 + l4*8;
        bf[fn] = *(const short8*)&Bs[row*64 + (kl ^ ((row & 7) << 3))];
      }
      // swapped operands: D rows = K-side (l), D cols = Q-side (s)
      #pragma unroll
      for (int fm = 0; fm < 4; ++fm)
        #pragma unroll
        for (int fn = 0; fn < 4; ++fn)
          acc[fm][fn] = __builtin_amdgcn_mfma_f32_16x16x32_bf16(bf[fn], af[fm], acc[fm][fn], 0, 0, 0);
    }
    __syncthreads();
  }

  // Epilogue: lane holds 4 consecutive l at fixed s -> float4 nt stores.
  float* Ob = Out + ((size_t)bh << 20);
  #pragma unroll
  for (int fm = 0; fm < 4; ++fm) {
    int srow = tm + wm + fm*16 + l15;
    #pragma unroll
    for (int fn = 0; fn < 4; ++fn) {
      int lcol = tn + wn + fn*16 + l4*4;
      __builtin_nontemporal_store(acc[fm][fn],
          (f32x4*)(Ob + ((size_t)srow << 10) + lcol));
    }
  }
}

extern "C" void kernel_launch(void* const* d_in, const int* in_sizes, int n_in,
                              void* d_out, int out_size, void* d_ws, size_t ws_size,
                              hipStream_t stream) {
  const float* Q   = (const float*)d_in[0];
  const float* Kv  = (const float*)d_in[1];
  const float* M1L = (const float*)d_in[2];
  const float* M1R = (const float*)d_in[3];
  const float* M2L = (const float*)d_in[4];
  const float* M2R = (const float*)d_in[5];
  const float* W   = (const float*)d_in[6];
  const int* per   = (const int*)d_in[7];
  float* Out       = (float*)d_out;

  const size_t qsz = (size_t)32 * 1024 * 256;     // 8388608 shorts each
  short* Qhat = (short*)d_ws;
  short* Khat = Qhat + qsz;
  short* Lbf  = Khat + qsz;
  const size_t need = (qsz * 2 + (size_t)4 * 131072) * sizeof(short);
  const bool usebf = (ws_size >= need);

  if (usebf) {
    conv_lr<<<dim3(128), dim3(256), 0, stream>>>(M1L, M1R, M2L, M2R, Lbf);
    monarch_transform3<true><<<dim3(256), dim3(512), 0, stream>>>(
        Q, Kv, M1L, M1R, M2L, M2R, Lbf, W, per, Qhat, Khat);
  } else {
    monarch_transform3<false><<<dim3(256), dim3(512), 0, stream>>>(
        Q, Kv, M1L, M1R, M2L, M2R, Lbf, W, per, Qhat, Khat);
  }

  score_gemm<<<dim3(2048), dim3(256), 0, stream>>>(Qhat, Khat, Out);
}